// Round 4
// baseline (1552.693 us; speedup 1.0000x reference)
//
#include <hip/hip_runtime.h>
#include <hip/hip_bf16.h>
#include <stdint.h>

// GraphSAGE layer, N=16384, F_IN=F_OUT=256.
// out = (adj@ (x@W1))/deg + x@W2 + bias
//   K0: WT[n][k] (bf16)  = transpose of [W1|W2]
//   K1: yT[n][m] (bf16)  = (x@W1)^T ;  z[m][n] (f32) = x@W2 + bias
//   K2 v4: split-K 2 (2 blocks/CU), 4 waves x (64x64) tiles over 64x256,
//          16 MFMA/wave/barrier, LDS frag reads 32KB/iter (was 48KB).
//   K3: out = (p0+p1)/(d0+d1) + z

typedef short bf16x8 __attribute__((ext_vector_type(8)));
typedef float f32x4  __attribute__((ext_vector_type(4)));

__device__ __forceinline__ uint32_t pack_bf16_rne(float lo, float hi) {
    uint32_t ul = __float_as_uint(lo);
    uint32_t uh = __float_as_uint(hi);
    ul = (ul + 0x7fffu + ((ul >> 16) & 1u)) >> 16;
    uh = (uh + 0x7fffu + ((uh >> 16) & 1u)) >> 16;
    return ul | (uh << 16);
}

__device__ __forceinline__ void gload_lds16(const void* g, void* l) {
    __builtin_amdgcn_global_load_lds(
        (__attribute__((address_space(1))) void*)g,
        (__attribute__((address_space(3))) void*)l, 16, 0, 0);
}

// ---------------- K0: transpose weight [512,256] f32 -> WT [512(n)][256(k)] bf16
__global__ __launch_bounds__(256) void k_transpose_w(const float* __restrict__ w,
                                                     uint16_t* __restrict__ wt) {
    int idx = blockIdx.x * 256 + threadIdx.x;   // 0..131071
    int n = idx >> 8;
    int k = idx & 255;
    int row = (n < 256) ? k : (256 + k);
    int col = (n < 256) ? n : (n - 256);
    uint32_t u = __float_as_uint(w[row * 256 + col]);
    u = (u + 0x7fffu + ((u >> 16) & 1u)) >> 16;
    wt[idx] = (uint16_t)u;
}

// ---------------- K1: small GEMM  [16384,256] @ [256,512] -> yT (cols 0..255) / z (cols 256..511)
__global__ __launch_bounds__(256) void k_small_gemm(const float* __restrict__ x,
                                                    const uint16_t* __restrict__ wt,
                                                    const float* __restrict__ bias,
                                                    uint16_t* __restrict__ yT,
                                                    float* __restrict__ z) {
    __shared__ uint16_t As[128 * 32];  // [m][k] bf16
    __shared__ uint16_t Bs[128 * 32];  // [n][k] bf16

    const int t  = threadIdx.x;
    const int ct = blockIdx.x;        // 0..3
    const int rt = blockIdx.y;        // 0..127
    const int m0 = rt * 128;
    const int n0 = ct * 128;

    const int lane = t & 63, w = t >> 6;
    const int wr = w >> 1, wc = w & 1;
    const int l15 = lane & 15, quad = lane >> 4;

    f32x4 acc[4][4] = {};

    float4 a_reg[4];
    uint4  b_reg[2];

#pragma unroll
    for (int i = 0; i < 4; ++i) {
        int f4 = t + 256 * i, row = f4 >> 3, c4 = f4 & 7;
        a_reg[i] = *(const float4*)(x + (m0 + row) * 256 + c4 * 4);
    }
#pragma unroll
    for (int i = 0; i < 2; ++i) {
        int u4 = t + 256 * i, n_l = u4 >> 2, part = u4 & 3;
        b_reg[i] = *(const uint4*)(wt + (n0 + n_l) * 256 + part * 8);
    }

    for (int kk = 0; kk < 8; ++kk) {
        __syncthreads();
#pragma unroll
        for (int i = 0; i < 4; ++i) {
            int f4 = t + 256 * i, row = f4 >> 3, c4 = f4 & 7;
            uint2 p;
            p.x = pack_bf16_rne(a_reg[i].x, a_reg[i].y);
            p.y = pack_bf16_rne(a_reg[i].z, a_reg[i].w);
            *(uint2*)(As + row * 32 + c4 * 4) = p;
        }
#pragma unroll
        for (int i = 0; i < 2; ++i) {
            int u4 = t + 256 * i, n_l = u4 >> 2, part = u4 & 3;
            *(uint4*)(Bs + n_l * 32 + part * 8) = b_reg[i];
        }
        if (kk < 7) {
            int k0 = (kk + 1) * 32;
#pragma unroll
            for (int i = 0; i < 4; ++i) {
                int f4 = t + 256 * i, row = f4 >> 3, c4 = f4 & 7;
                a_reg[i] = *(const float4*)(x + (m0 + row) * 256 + k0 + c4 * 4);
            }
#pragma unroll
            for (int i = 0; i < 2; ++i) {
                int u4 = t + 256 * i, n_l = u4 >> 2, part = u4 & 3;
                b_reg[i] = *(const uint4*)(wt + (n0 + n_l) * 256 + k0 + part * 8);
            }
        }
        __syncthreads();

        bf16x8 a_frag[4], b_frag[4];
#pragma unroll
        for (int fr = 0; fr < 4; ++fr)
            a_frag[fr] = *(const bf16x8*)(As + (wr * 64 + fr * 16 + l15) * 32 + quad * 8);
#pragma unroll
        for (int fc = 0; fc < 4; ++fc)
            b_frag[fc] = *(const bf16x8*)(Bs + (wc * 64 + fc * 16 + l15) * 32 + quad * 8);
#pragma unroll
        for (int fr = 0; fr < 4; ++fr)
#pragma unroll
            for (int fc = 0; fc < 4; ++fc)
                acc[fr][fc] = __builtin_amdgcn_mfma_f32_16x16x32_bf16(
                    a_frag[fr], b_frag[fc], acc[fr][fc], 0, 0, 0);
    }

    if (ct < 2) {
#pragma unroll
        for (int fr = 0; fr < 4; ++fr) {
            int m_base = m0 + wr * 64 + fr * 16 + quad * 4;
#pragma unroll
            for (int fc = 0; fc < 4; ++fc) {
                int n_g = n0 + wc * 64 + fc * 16 + l15;   // 0..255
                uint2 pp;
                pp.x = pack_bf16_rne(acc[fr][fc][0], acc[fr][fc][1]);
                pp.y = pack_bf16_rne(acc[fr][fc][2], acc[fr][fc][3]);
                *(uint2*)(yT + (size_t)n_g * 16384 + m_base) = pp;
            }
        }
    } else {
#pragma unroll
        for (int fr = 0; fr < 4; ++fr) {
            int m_base = m0 + wr * 64 + fr * 16 + quad * 4;
#pragma unroll
            for (int fc = 0; fc < 4; ++fc) {
                int n_g = (n0 - 256) + wc * 64 + fc * 16 + l15;  // 0..255
                float bv = bias[n_g];
#pragma unroll
                for (int r = 0; r < 4; ++r)
                    z[(size_t)(m_base + r) * 256 + n_g] = acc[fr][fc][r] + bv;
            }
        }
    }
}

// ---------------- K2 v4: partial[ky] = adj[:, ky-half] @ y[ky-half, :]
// grid (256 row-tiles, 2 k-halves) = 512 blocks = 2/CU; 256 threads (4 waves),
// wave tile 64x64 over block tile 64x256; BK=32, 256 iters; dbuf LDS 42 KB.
#define A_STRIDE 40                 // 64 rows x 40 halfwords (80B row, conflict-free)
#define A_SZ (64 * A_STRIDE)
#define B_SZ (256 * 32)             // XOR-swizzled, unpadded (global_load_lds dest)
#define KITER 256
__global__ __launch_bounds__(256, 2) void k_big_gemm(const int* __restrict__ adj,
                                                     const uint16_t* __restrict__ yT,
                                                     float* __restrict__ part,
                                                     int* __restrict__ degw) {
    __shared__ uint16_t As_f[2 * A_SZ];   //  10 KB
    __shared__ uint16_t Bs_f[2 * B_SZ];   //  32 KB

    const int t = threadIdx.x;
    const int m0 = blockIdx.x * 64;
    const int ky = blockIdx.y;                     // k-half
    const int kbase = ky * 8192;
    const int lane = t & 63, w = t >> 6;           // w 0..3 = column group
    const int l15 = lane & 15, quad = lane >> 4;

    f32x4 acc[4][4] = {};                          // [row frag][col frag]

    // ---- A staging: 64 rows x 32 ints / iter = 512 int4; 2 per thread
    const int a_row = t >> 2;                      // 0..63
    const int c0 = (t & 3), c1 = (t & 3) + 4;      // int4 chunk ids (k = 4c..4c+3)
    const int4* pa0 = (const int4*)(adj + (size_t)(m0 + a_row) * 16384 + kbase) + c0;
    const int4* pa1 = pa0 + 4;                     // chunk c1 = c0+4
    const int a_lds0 = a_row * A_STRIDE + c0 * 4;  // halfword offsets
    const int a_lds1 = a_row * A_STRIDE + c1 * 4;

    // ---- B staging: 256 rows x 32 bf16 / iter = 1024 16B slots; 4 per thread
    const uint16_t* pbg[4];
    int b_ldsbase[4];
#pragma unroll
    for (int i = 0; i < 4; ++i) {
        int base = w * 64 + i * 256;               // wave-uniform slot base
        int s = base + lane;
        int bn = s >> 2;
        int bc = (s & 3) ^ ((bn >> 1) & 3);        // XOR swizzle absorbed in global addr
        pbg[i] = yT + (size_t)bn * 16384 + kbase + bc * 8;
        b_ldsbase[i] = base * 8;                   // halfword offset (lane adds 8 hw)
    }

    // ---- prologue: fill buffer 0
#pragma unroll
    for (int i = 0; i < 4; ++i) {
        gload_lds16(pbg[i], &Bs_f[b_ldsbase[i]]);
        pbg[i] += 32;
    }
    int4 a0 = pa0[0]; pa0 += 8;
    int4 a1 = pa1[0]; pa1 += 8;
    int degp = a0.x + a0.y + a0.z + a0.w + a1.x + a1.y + a1.z + a1.w;
    {
        uint2 pv;
        pv.x = (uint32_t)(a0.x | (a0.y << 16)) * 0x3F80u;
        pv.y = (uint32_t)(a0.z | (a0.w << 16)) * 0x3F80u;
        *(uint2*)&As_f[a_lds0] = pv;
        pv.x = (uint32_t)(a1.x | (a1.y << 16)) * 0x3F80u;
        pv.y = (uint32_t)(a1.z | (a1.w << 16)) * 0x3F80u;
        *(uint2*)&As_f[a_lds1] = pv;
    }
    __syncthreads();

    for (int kk = 0; kk < KITER; ++kk) {
        const int p = kk & 1;
        int4 an0, an1;
        if (kk < KITER - 1) {
            // issue next-iter loads right after the barrier; they stay in
            // flight through the fragread+MFMA phase below
            an0 = pa0[0]; pa0 += 8;
            an1 = pa1[0]; pa1 += 8;
#pragma unroll
            for (int i = 0; i < 4; ++i) {
                gload_lds16(pbg[i], &Bs_f[(1 - p) * B_SZ + b_ldsbase[i]]);
                pbg[i] += 32;
            }
        }

        const uint16_t* Ar = As_f + p * A_SZ;
        const uint16_t* Br = Bs_f + p * B_SZ;
        bf16x8 af[4], bfr[4];
#pragma unroll
        for (int fr = 0; fr < 4; ++fr) {
            int row = fr * 16 + l15;
            af[fr] = *(const bf16x8*)(Ar + row * A_STRIDE + quad * 8);
        }
#pragma unroll
        for (int fc = 0; fc < 4; ++fc) {
            int n = w * 64 + fc * 16 + l15;
            int cs = quad ^ ((n >> 1) & 3);
            bfr[fc] = *(const bf16x8*)(Br + n * 32 + cs * 8);
        }
#pragma unroll
        for (int fr = 0; fr < 4; ++fr)
#pragma unroll
            for (int fc = 0; fc < 4; ++fc)
                acc[fr][fc] = __builtin_amdgcn_mfma_f32_16x16x32_bf16(
                    af[fr], bfr[fc], acc[fr][fc], 0, 0, 0);

        if (kk < KITER - 1) {
            degp += an0.x + an0.y + an0.z + an0.w + an1.x + an1.y + an1.z + an1.w;
            uint2 pv;
            pv.x = (uint32_t)(an0.x | (an0.y << 16)) * 0x3F80u;
            pv.y = (uint32_t)(an0.z | (an0.w << 16)) * 0x3F80u;
            *(uint2*)&As_f[(1 - p) * A_SZ + a_lds0] = pv;
            pv.x = (uint32_t)(an1.x | (an1.y << 16)) * 0x3F80u;
            pv.y = (uint32_t)(an1.z | (an1.w << 16)) * 0x3F80u;
            *(uint2*)&As_f[(1 - p) * A_SZ + a_lds1] = pv;
        }
        __syncthreads();
    }

    // partial deg: row a_row owned by 4 consecutive lanes (t&3)
    degp += __shfl_down(degp, 2);
    degp += __shfl_down(degp, 1);
    if ((t & 3) == 0) degw[ky * 16384 + m0 + a_row] = degp;

    // partial C
    float* pc = part + (size_t)ky * 16384 * 256;
#pragma unroll
    for (int fr = 0; fr < 4; ++fr) {
#pragma unroll
        for (int r = 0; r < 4; ++r) {
            int m_l = fr * 16 + quad * 4 + r;
            size_t mrow = (size_t)(m0 + m_l) * 256;
#pragma unroll
            for (int fc = 0; fc < 4; ++fc) {
                int n_g = w * 64 + fc * 16 + l15;
                pc[mrow + n_g] = acc[fr][fc][r];
            }
        }
    }
}

// ---------------- K3: out = (p0+p1)/(d0+d1) + z
__global__ __launch_bounds__(256) void k_reduce(const float* __restrict__ part,
                                                const int* __restrict__ degw,
                                                const float* __restrict__ z,
                                                float* __restrict__ out) {
    int i4 = blockIdx.x * 256 + threadIdx.x;       // float4 index, 64 per row
    int m = i4 >> 6;
    float4 p0 = ((const float4*)part)[i4];
    float4 p1 = ((const float4*)part)[i4 + 16384 * 64];
    float4 zz = ((const float4*)z)[i4];
    float inv = 1.0f / (float)(degw[m] + degw[16384 + m]);
    float4 o;
    o.x = (p0.x + p1.x) * inv + zz.x;
    o.y = (p0.y + p1.y) * inv + zz.y;
    o.z = (p0.z + p1.z) * inv + zz.z;
    o.w = (p0.w + p1.w) * inv + zz.w;
    ((float4*)out)[i4] = o;
}

extern "C" void kernel_launch(void* const* d_in, const int* in_sizes, int n_in,
                              void* d_out, int out_size, void* d_ws, size_t ws_size,
                              hipStream_t stream) {
    const float* x      = (const float*)d_in[0];
    const int*   adj    = (const int*)d_in[1];
    const float* weight = (const float*)d_in[2];
    const float* bias   = (const float*)d_in[3];
    float* out = (float*)d_out;

    // ws: WT 256KB | yT 8MB | z 16MB | part 33.5MB | degw 128KB
    uint16_t* wt   = (uint16_t*)d_ws;
    uint16_t* yT   = (uint16_t*)((char*)d_ws + 262144);
    float*    z    = (float*)((char*)d_ws + 262144 + 8388608);
    float*    partb= (float*)((char*)d_ws + 262144 + 8388608 + 16777216);
    int*      degw = (int*)((char*)d_ws + 262144 + 8388608 + 16777216 + 33554432);

    k_transpose_w<<<512, 256, 0, stream>>>(weight, wt);
    k_small_gemm<<<dim3(4, 128), 256, 0, stream>>>(x, wt, bias, yT, z);
    k_big_gemm<<<dim3(256, 2), 256, 0, stream>>>(adj, yT, partb, degw);
    k_reduce<<<4096, 256, 0, stream>>>(partb, degw, z, out);
}

// Round 5
// 1487.454 us; speedup vs baseline: 1.0439x; 1.0439x over previous
//
#include <hip/hip_runtime.h>
#include <hip/hip_bf16.h>
#include <stdint.h>

// GraphSAGE layer, N=16384, F_IN=F_OUT=256.
// out = (adj@ (x@W1))/deg + x@W2 + bias
//   K0: WT[n][k] (bf16)  = transpose of [W1|W2]
//   K1: yT[n][m] (bf16)  = (x@W1)^T ;  z[m][n] (f32) = x@W2 + bias
//   K2 v5: v3 structure (split-K 2, 512 thr / 8 waves of 32x64, BK=32,
//          dbuf LDS, XOR-swizzled B via global_load_lds) + A PREFETCH DEPTH 2:
//          the adj int4 packed in iter kk was loaded at kk-2, so the pack
//          never stalls on the ~900-cyc HBM latency (it is guaranteed
//          complete by the previous barrier's vmcnt(0) drain).
//   K3: out = (p0+p1)/(d0+d1) + z

typedef short bf16x8 __attribute__((ext_vector_type(8)));
typedef float f32x4  __attribute__((ext_vector_type(4)));

__device__ __forceinline__ uint32_t pack_bf16_rne(float lo, float hi) {
    uint32_t ul = __float_as_uint(lo);
    uint32_t uh = __float_as_uint(hi);
    ul = (ul + 0x7fffu + ((ul >> 16) & 1u)) >> 16;
    uh = (uh + 0x7fffu + ((uh >> 16) & 1u)) >> 16;
    return ul | (uh << 16);
}

__device__ __forceinline__ void gload_lds16(const void* g, void* l) {
    __builtin_amdgcn_global_load_lds(
        (__attribute__((address_space(1))) void*)g,
        (__attribute__((address_space(3))) void*)l, 16, 0, 0);
}

// ---------------- K0: transpose weight [512,256] f32 -> WT [512(n)][256(k)] bf16
__global__ __launch_bounds__(256) void k_transpose_w(const float* __restrict__ w,
                                                     uint16_t* __restrict__ wt) {
    int idx = blockIdx.x * 256 + threadIdx.x;   // 0..131071
    int n = idx >> 8;
    int k = idx & 255;
    int row = (n < 256) ? k : (256 + k);
    int col = (n < 256) ? n : (n - 256);
    uint32_t u = __float_as_uint(w[row * 256 + col]);
    u = (u + 0x7fffu + ((u >> 16) & 1u)) >> 16;
    wt[idx] = (uint16_t)u;
}

// ---------------- K1: small GEMM  [16384,256] @ [256,512] -> yT (cols 0..255) / z (cols 256..511)
__global__ __launch_bounds__(256) void k_small_gemm(const float* __restrict__ x,
                                                    const uint16_t* __restrict__ wt,
                                                    const float* __restrict__ bias,
                                                    uint16_t* __restrict__ yT,
                                                    float* __restrict__ z) {
    __shared__ uint16_t As[128 * 32];  // [m][k] bf16
    __shared__ uint16_t Bs[128 * 32];  // [n][k] bf16

    const int t  = threadIdx.x;
    const int ct = blockIdx.x;        // 0..3
    const int rt = blockIdx.y;        // 0..127
    const int m0 = rt * 128;
    const int n0 = ct * 128;

    const int lane = t & 63, w = t >> 6;
    const int wr = w >> 1, wc = w & 1;
    const int l15 = lane & 15, quad = lane >> 4;

    f32x4 acc[4][4] = {};

    float4 a_reg[4];
    uint4  b_reg[2];

#pragma unroll
    for (int i = 0; i < 4; ++i) {
        int f4 = t + 256 * i, row = f4 >> 3, c4 = f4 & 7;
        a_reg[i] = *(const float4*)(x + (m0 + row) * 256 + c4 * 4);
    }
#pragma unroll
    for (int i = 0; i < 2; ++i) {
        int u4 = t + 256 * i, n_l = u4 >> 2, part = u4 & 3;
        b_reg[i] = *(const uint4*)(wt + (n0 + n_l) * 256 + part * 8);
    }

    for (int kk = 0; kk < 8; ++kk) {
        __syncthreads();
#pragma unroll
        for (int i = 0; i < 4; ++i) {
            int f4 = t + 256 * i, row = f4 >> 3, c4 = f4 & 7;
            uint2 p;
            p.x = pack_bf16_rne(a_reg[i].x, a_reg[i].y);
            p.y = pack_bf16_rne(a_reg[i].z, a_reg[i].w);
            *(uint2*)(As + row * 32 + c4 * 4) = p;
        }
#pragma unroll
        for (int i = 0; i < 2; ++i) {
            int u4 = t + 256 * i, n_l = u4 >> 2, part = u4 & 3;
            *(uint4*)(Bs + n_l * 32 + part * 8) = b_reg[i];
        }
        if (kk < 7) {
            int k0 = (kk + 1) * 32;
#pragma unroll
            for (int i = 0; i < 4; ++i) {
                int f4 = t + 256 * i, row = f4 >> 3, c4 = f4 & 7;
                a_reg[i] = *(const float4*)(x + (m0 + row) * 256 + k0 + c4 * 4);
            }
#pragma unroll
            for (int i = 0; i < 2; ++i) {
                int u4 = t + 256 * i, n_l = u4 >> 2, part = u4 & 3;
                b_reg[i] = *(const uint4*)(wt + (n0 + n_l) * 256 + k0 + part * 8);
            }
        }
        __syncthreads();

        bf16x8 a_frag[4], b_frag[4];
#pragma unroll
        for (int fr = 0; fr < 4; ++fr)
            a_frag[fr] = *(const bf16x8*)(As + (wr * 64 + fr * 16 + l15) * 32 + quad * 8);
#pragma unroll
        for (int fc = 0; fc < 4; ++fc)
            b_frag[fc] = *(const bf16x8*)(Bs + (wc * 64 + fc * 16 + l15) * 32 + quad * 8);
#pragma unroll
        for (int fr = 0; fr < 4; ++fr)
#pragma unroll
            for (int fc = 0; fc < 4; ++fc)
                acc[fr][fc] = __builtin_amdgcn_mfma_f32_16x16x32_bf16(
                    a_frag[fr], b_frag[fc], acc[fr][fc], 0, 0, 0);
    }

    if (ct < 2) {
#pragma unroll
        for (int fr = 0; fr < 4; ++fr) {
            int m_base = m0 + wr * 64 + fr * 16 + quad * 4;
#pragma unroll
            for (int fc = 0; fc < 4; ++fc) {
                int n_g = n0 + wc * 64 + fc * 16 + l15;   // 0..255
                uint2 pp;
                pp.x = pack_bf16_rne(acc[fr][fc][0], acc[fr][fc][1]);
                pp.y = pack_bf16_rne(acc[fr][fc][2], acc[fr][fc][3]);
                *(uint2*)(yT + (size_t)n_g * 16384 + m_base) = pp;
            }
        }
    } else {
#pragma unroll
        for (int fr = 0; fr < 4; ++fr) {
            int m_base = m0 + wr * 64 + fr * 16 + quad * 4;
#pragma unroll
            for (int fc = 0; fc < 4; ++fc) {
                int n_g = (n0 - 256) + wc * 64 + fc * 16 + l15;  // 0..255
                float bv = bias[n_g];
#pragma unroll
                for (int r = 0; r < 4; ++r)
                    z[(size_t)(m_base + r) * 256 + n_g] = acc[fr][fc][r] + bv;
            }
        }
    }
}

// ---------------- K2 v5: partial[ky] = adj[:, ky-half] @ y[ky-half, :]
// grid (256 row-tiles, 2 k-halves), 512 threads (8 waves; wave = 32x64),
// BK=32, 256 iters, dbuf LDS, A prefetch depth 2.
#define A_STRIDE 40                 // 64 rows x 40 halfwords (80B row = conflict-free)
#define A_SZ (64 * A_STRIDE)
#define B_SZ (256 * 32)             // XOR-swizzled, unpadded (global_load_lds dest)
#define KITER 256
__global__ __launch_bounds__(512, 4) void k_big_gemm(const int* __restrict__ adj,
                                                     const uint16_t* __restrict__ yT,
                                                     float* __restrict__ part,
                                                     int* __restrict__ degw) {
    __shared__ uint16_t As_f[2 * A_SZ];   //  10 KB
    __shared__ uint16_t Bs_f[2 * B_SZ];   //  32 KB

    const int t = threadIdx.x;
    const int m0 = blockIdx.x * 64;
    const int ky = blockIdx.y;                     // k-half
    const int kbase = ky * 8192;                   // element offset into k
    const int lane = t & 63, w = t >> 6;
    const int wr = w >> 2, wc = w & 3;             // wave: 2 row frags, 4 col frags
    const int l15 = lane & 15, quad = lane >> 4;

    f32x4 acc[2][4] = {};

    // A staging: 64 rows x 32 ints / iter = 512 int4, one per thread
    const int a_n = t >> 3, a_c4 = t & 7;
    const int4* pa4 = (const int4*)(adj + (size_t)(m0 + a_n) * 16384 + kbase) + a_c4;
    const int a_lds = a_n * A_STRIDE + a_c4 * 4;

    // B staging: 256 rows x 32 bf16 / iter = 1024 16B slots, 2 global_load_lds/thread
    const uint16_t* pbg[2];
    int b_ldsbase[2];
#pragma unroll
    for (int i = 0; i < 2; ++i) {
        int base = (w * 2 + i) * 64;
        int s = base + lane;
        int bn = s >> 2;
        int bc = (s & 3) ^ ((bn >> 1) & 3);        // XOR swizzle absorbed in global addr
        pbg[i] = yT + (size_t)bn * 16384 + kbase + bc * 8;
        b_ldsbase[i] = base * 8;
    }

    // ---- prologue: A for k-steps 0 and 1; B + LDS for k-step 0
    int4 aP = pa4[0];            // k-step 0 (packed in prologue)
    int4 aB = pa4[8];            // k-step 1 (packed at kk=0)
    pa4 += 16;
#pragma unroll
    for (int i = 0; i < 2; ++i) {
        gload_lds16(pbg[i], &Bs_f[b_ldsbase[i]]);
        pbg[i] += 32;
    }
    int degp = aP.x + aP.y + aP.z + aP.w;
    {
        uint2 pv;
        pv.x = (uint32_t)(aP.x | (aP.y << 16)) * 0x3F80u;
        pv.y = (uint32_t)(aP.z | (aP.w << 16)) * 0x3F80u;
        *(uint2*)&As_f[a_lds] = pv;
    }
    __syncthreads();

    for (int kk = 0; kk < KITER; ++kk) {
        const int p = kk & 1;
        // issue next-next A load FIRST (longest-latency stream, max in-flight)
        int4 aNew;
        if (kk < KITER - 2) { aNew = pa4[0]; pa4 += 8; }
        if (kk < KITER - 1) {
#pragma unroll
            for (int i = 0; i < 2; ++i) {
                gload_lds16(pbg[i], &Bs_f[(1 - p) * B_SZ + b_ldsbase[i]]);
                pbg[i] += 32;
            }
        }

        const uint16_t* Ar = As_f + p * A_SZ;
        const uint16_t* Br = Bs_f + p * B_SZ;
        bf16x8 af[2], bfr[4];
#pragma unroll
        for (int fr = 0; fr < 2; ++fr) {
            int row = wr * 32 + fr * 16 + l15;
            af[fr] = *(const bf16x8*)(Ar + row * A_STRIDE + quad * 8);
        }
#pragma unroll
        for (int fc = 0; fc < 4; ++fc) {
            int n = wc * 64 + fc * 16 + l15;
            int cs = quad ^ ((n >> 1) & 3);
            bfr[fc] = *(const bf16x8*)(Br + n * 32 + cs * 8);
        }
#pragma unroll
        for (int fr = 0; fr < 2; ++fr)
#pragma unroll
            for (int fc = 0; fc < 4; ++fc)
                acc[fr][fc] = __builtin_amdgcn_mfma_f32_16x16x32_bf16(
                    af[fr], bfr[fc], acc[fr][fc], 0, 0, 0);

        if (kk < KITER - 1) {
            // aB holds k-step kk+1, loaded at iter kk-1 (or prologue):
            // already drained by the previous barrier -> no vmcnt stall here
            degp += aB.x + aB.y + aB.z + aB.w;
            uint2 pv;
            pv.x = (uint32_t)(aB.x | (aB.y << 16)) * 0x3F80u;
            pv.y = (uint32_t)(aB.z | (aB.w << 16)) * 0x3F80u;
            *(uint2*)&As_f[(1 - p) * A_SZ + a_lds] = pv;
        }
        if (kk < KITER - 2) aB = aNew;
        __syncthreads();
    }

    // partial deg: row a_n owned by 8 consecutive lanes
    degp += __shfl_down(degp, 4);
    degp += __shfl_down(degp, 2);
    degp += __shfl_down(degp, 1);
    if ((t & 7) == 0) degw[ky * 16384 + m0 + a_n] = degp;

    // partial C
    float* pc = part + (size_t)ky * 16384 * 256;
#pragma unroll
    for (int fr = 0; fr < 2; ++fr) {
#pragma unroll
        for (int r = 0; r < 4; ++r) {
            int m_l = wr * 32 + fr * 16 + quad * 4 + r;
            size_t mrow = (size_t)(m0 + m_l) * 256;
#pragma unroll
            for (int fc = 0; fc < 4; ++fc) {
                int n_g = wc * 64 + fc * 16 + l15;
                pc[mrow + n_g] = acc[fr][fc][r];
            }
        }
    }
}

// ---------------- K3: out = (p0+p1)/(d0+d1) + z
__global__ __launch_bounds__(256) void k_reduce(const float* __restrict__ part,
                                                const int* __restrict__ degw,
                                                const float* __restrict__ z,
                                                float* __restrict__ out) {
    int i4 = blockIdx.x * 256 + threadIdx.x;       // float4 index, 64 per row
    int m = i4 >> 6;
    float4 p0 = ((const float4*)part)[i4];
    float4 p1 = ((const float4*)part)[i4 + 16384 * 64];
    float4 zz = ((const float4*)z)[i4];
    float inv = 1.0f / (float)(degw[m] + degw[16384 + m]);
    float4 o;
    o.x = (p0.x + p1.x) * inv + zz.x;
    o.y = (p0.y + p1.y) * inv + zz.y;
    o.z = (p0.z + p1.z) * inv + zz.z;
    o.w = (p0.w + p1.w) * inv + zz.w;
    ((float4*)out)[i4] = o;
}

extern "C" void kernel_launch(void* const* d_in, const int* in_sizes, int n_in,
                              void* d_out, int out_size, void* d_ws, size_t ws_size,
                              hipStream_t stream) {
    const float* x      = (const float*)d_in[0];
    const int*   adj    = (const int*)d_in[1];
    const float* weight = (const float*)d_in[2];
    const float* bias   = (const float*)d_in[3];
    float* out = (float*)d_out;

    // ws: WT 256KB | yT 8MB | z 16MB | part 33.5MB | degw 128KB
    uint16_t* wt   = (uint16_t*)d_ws;
    uint16_t* yT   = (uint16_t*)((char*)d_ws + 262144);
    float*    z    = (float*)((char*)d_ws + 262144 + 8388608);
    float*    partb= (float*)((char*)d_ws + 262144 + 8388608 + 16777216);
    int*      degw = (int*)((char*)d_ws + 262144 + 8388608 + 16777216 + 33554432);

    k_transpose_w<<<512, 256, 0, stream>>>(weight, wt);
    k_small_gemm<<<dim3(4, 128), 256, 0, stream>>>(x, wt, bias, yT, z);
    k_big_gemm<<<dim3(256, 2), 512, 0, stream>>>(adj, yT, partb, degw);
    k_reduce<<<4096, 256, 0, stream>>>(partb, degw, z, out);
}